// Round 14
// baseline (1198.353 us; speedup 1.0000x reference)
//
#include <hip/hip_runtime.h>
#include <stdint.h>

#define NB 512
#define NT 64
#define NF 128
#define NU 1024
#define NG 4096
#define NS 32

typedef __attribute__((ext_vector_type(8))) short short8;
typedef __attribute__((ext_vector_type(4))) float f32x4;
typedef __attribute__((ext_vector_type(16))) float f32x16;
typedef __attribute__((ext_vector_type(4))) unsigned int u32x4;

__device__ __forceinline__ float sigm(float x) { return 1.0f / (1.0f + __expf(-x)); }
__device__ __forceinline__ float tanh_f(float x) {
  float ax = fabsf(x);
  float e = __expf(2.0f * ax);        // e >= 1; inf ok
  float t = 1.0f - 2.0f / (e + 1.0f);
  return copysignf(t, x);
}
__device__ __forceinline__ unsigned short f2bf(float f) {
  union { float f; unsigned u; } v; v.f = f;
  unsigned r = v.u + 0x7fffu + ((v.u >> 16) & 1u);  // RNE
  return (unsigned short)(r >> 16);
}

// R3-proven h-exchange: write-through (sc0 sc1) stores -> memory-side L3;
// consumers read with sc0 sc1 bypass loads. No fences, no L2 maintenance.
// SESSION LESSONS: (R4) RELEASE fences in-loop: FETCH x6.5. (R5/R6/R10/R11/R12)
// VGPR envelope is heuristically capped at 128 (dynamic LDS hides the 1-block/CU
// occupancy from the compiler) — state beyond that silently spills: FETCH +GBs.
// This redesign: 64-row blocks via 32x32x16 MFMA (acc 32 VGPRs not 64) to
// HALVE the per-XCD B L2 stream (16->8 MB/step), the dominant floor term.
__device__ __forceinline__ void coh_store_bf16(unsigned short* p, unsigned v) {
  asm volatile("global_store_short %0, %1, off sc0 sc1" :: "v"(p), "v"(v) : "memory");
}

// ---- 32-block GROUP barrier (blocks sharing m_blk = the h-row dependency) ----
__device__ __forceinline__ void gbar_grp(unsigned* gf, int u_blk, unsigned gen) {
  __syncthreads();   // drains vmcnt -> write-through h stores visible
  if (threadIdx.x == 0)
    __hip_atomic_store(gf + u_blk, gen, __ATOMIC_RELAXED, __HIP_MEMORY_SCOPE_AGENT);
  if (threadIdx.x < 32) {
    while (__hip_atomic_load(gf + threadIdx.x, __ATOMIC_RELAXED, __HIP_MEMORY_SCOPE_AGENT) < gen)
      __builtin_amdgcn_s_sleep(1);
  }
  __syncthreads();
}

// ---------------- one fused LSTM step (64 rows x 32 units x 4 gates) ----------------
// 8 waves = kh(2 K-halves) x g(4 gates). Wave (kh,g): two 32x32 tiles (row-halves)
// over its K-half for gate g -> acc = 2 x f32x16. B frag = 16B/lane (8 consecutive
// k for col lane&31, k-group lane>>5) — same packed buffer as before.
// Exchange: all 8 waves write acc to LDS [slot][elem][lane] (scalar, conflict-free);
// every thread then sums 4 gates x 2 kh for its 4 (row,unit) cells and applies gates.
template <int KX>
__device__ __forceinline__ void do_step(
    const unsigned short* __restrict__ hIn,   // [512][1024] bf16 (read via sc0 sc1)
    const unsigned short* __restrict__ Bp,    // packed [128][4096][8] bf16
    const unsigned short* __restrict__ Xp,    // [64][512][128] bf16 or null
    const unsigned short* __restrict__ W1p,   // packed [16][4096][8] bf16 or null
    int tstep, f32x4 bA, f32x4& cst,
    unsigned short* __restrict__ hOut, unsigned short* __restrict__ hOut2,
    unsigned short* lds,
    int r0, int u0, int kh, int g, int tid)
{
  constexpr int ROWB = (NU + KX) * 2;         // LDS row bytes
  const int lane = tid & 63;
  const int lu = lane & 31;                   // A-row / B-col within tile
  const int lk = lane >> 5;                   // k-group (8 elems each)

  // ---- stage A (64 h rows [+x]) into LDS, XOR-swizzled; two 8-batches ----
  {
    u32x4 ta[8], tb[8];
    int la[8], lb[8];
#pragma unroll
    for (int it = 0; it < 8; ++it) {
      int i = tid + it * 512;
      int r = i >> 7, cb = i & 127;
      la[it] = r * ROWB + ((cb * 16) ^ ((r & 7) << 4));
      const unsigned short* gp = hIn + (size_t)(r0 + r) * NU + cb * 8;
      asm volatile("global_load_dwordx4 %0, %1, off sc0 sc1" : "=v"(ta[it]) : "v"(gp));
    }
#pragma unroll
    for (int it = 0; it < 8; ++it) {
      int i = tid + (8 + it) * 512;
      int r = i >> 7, cb = i & 127;
      lb[it] = r * ROWB + ((cb * 16) ^ ((r & 7) << 4));
      const unsigned short* gp = hIn + (size_t)(r0 + r) * NU + cb * 8;
      asm volatile("global_load_dwordx4 %0, %1, off sc0 sc1" : "=v"(tb[it]) : "v"(gp));
    }
    if constexpr (KX > 0) {
      u32x4 tx[2]; int ox[2];
#pragma unroll
      for (int it = 0; it < 2; ++it) {
        int i = tid + it * 512;                 // 64 rows x 16 chunks
        int r = i >> 4, cb = i & 15;
        ox[it] = r * ROWB + ((NU * 2 + cb * 16) ^ ((r & 7) << 4));
        const unsigned short* gp = Xp + ((size_t)tstep * NB + (r0 + r)) * NF + cb * 8;
        asm volatile("global_load_dwordx4 %0, %1, off" : "=v"(tx[it]) : "v"(gp));
      }
      asm volatile("s_waitcnt vmcnt(10)" ::: "memory");
      __builtin_amdgcn_sched_barrier(0);
#pragma unroll
      for (int it = 0; it < 8; ++it) *(u32x4*)((char*)lds + la[it]) = ta[it];
      asm volatile("s_waitcnt vmcnt(2)" ::: "memory");
      __builtin_amdgcn_sched_barrier(0);
#pragma unroll
      for (int it = 0; it < 8; ++it) *(u32x4*)((char*)lds + lb[it]) = tb[it];
      asm volatile("s_waitcnt vmcnt(0)" ::: "memory");
      __builtin_amdgcn_sched_barrier(0);
#pragma unroll
      for (int it = 0; it < 2; ++it) *(u32x4*)((char*)lds + ox[it]) = tx[it];
    } else {
      asm volatile("s_waitcnt vmcnt(8)" ::: "memory");
      __builtin_amdgcn_sched_barrier(0);
#pragma unroll
      for (int it = 0; it < 8; ++it) *(u32x4*)((char*)lds + la[it]) = ta[it];
      asm volatile("s_waitcnt vmcnt(0)" ::: "memory");
      __builtin_amdgcn_sched_barrier(0);
#pragma unroll
      for (int it = 0; it < 8; ++it) *(u32x4*)((char*)lds + lb[it]) = tb[it];
    }
  }
  __syncthreads();

  f32x16 acc0 = (f32x16)0.0f;   // rows [0,32)
  f32x16 acc1 = (f32x16)0.0f;   // rows [32,64)

  const char* ldsb = (const char*)lds;
  const int axor = (lane & 7) << 4;
  const int arow0 = lu * ROWB;
  const int arow1 = (32 + lu) * ROWB;
  const int kbase = kh * 1024;                 // byte base of this K-half in an A row
  const size_t cB = (size_t)g * NU + u0 + lu;  // packed-B column (gate g, unit col)

  // 2-deep B prefetch (named regs, parity-static under unroll 4 — proven pattern)
  short8 nb0 = *(const short8*)(Bp + ((size_t)(kh * 64 + 0 + lk) * NG + cB) * 8);
  short8 nb1 = *(const short8*)(Bp + ((size_t)(kh * 64 + 2 + lk) * NG + cB) * 8);
#pragma unroll 4
  for (int kc = 0; kc < 32; ++kc) {
    short8 bb = (kc & 1) ? nb1 : nb0;
    if (kc < 30) {
      short8 nv = *(const short8*)(Bp + ((size_t)(kh * 64 + (kc + 2) * 2 + lk) * NG + cB) * 8);
      if (kc & 1) nb1 = nv; else nb0 = nv;
    }
    int kb = (kbase + kc * 32 + lk * 16) ^ axor;
    short8 a0 = *(const short8*)(ldsb + arow0 + kb);
    short8 a1 = *(const short8*)(ldsb + arow1 + kb);
    acc0 = __builtin_amdgcn_mfma_f32_32x32x16_bf16(a0, bb, acc0, 0, 0, 0);
    acc1 = __builtin_amdgcn_mfma_f32_32x32x16_bf16(a1, bb, acc1, 0, 0, 0);
  }
  if constexpr (KX > 0) {                      // x-part: K=128, kh owns 64
#pragma unroll
    for (int kx = 0; kx < 4; ++kx) {
      short8 bb = *(const short8*)(W1p + ((size_t)(kh * 8 + kx * 2 + lk) * NG + cB) * 8);
      int kb = (NU * 2 + kh * 128 + kx * 32 + lk * 16) ^ axor;
      short8 a0 = *(const short8*)(ldsb + arow0 + kb);
      short8 a1 = *(const short8*)(ldsb + arow1 + kb);
      acc0 = __builtin_amdgcn_mfma_f32_32x32x16_bf16(a0, bb, acc0, 0, 0, 0);
      acc1 = __builtin_amdgcn_mfma_f32_32x32x16_bf16(a1, bb, acc1, 0, 0, 0);
    }
  }

  // ---- exchange: all waves -> LDS [slot][elem][lane] (64KB, conflict-free) ----
  __syncthreads();
  float* ex = (float*)lds;
  const int w8 = kh * 4 + g;
#pragma unroll
  for (int e = 0; e < 16; ++e) {
    ex[(w8 * 2 + 0) * 1024 + e * 64 + lane] = acc0[e];
    ex[(w8 * 2 + 1) * 1024 + e * 64 + lane] = acc1[e];
  }
  __syncthreads();

  // ---- epilogue: thread owns 4 cells (rows rb..rb+3, unit u); all 8 waves ----
  // C/D map (32x32): col=lane&31, row=(reg&3)+8*(reg>>2)+4*(lane>>5).
  const int u = tid & 31;
  const int rb = (tid >> 5) << 2;              // 4-aligned row base, 0..60
  const int rh = tid >> 8;                     // row-half (tile)
  const int c4 = (tid >> 6) & 3;               // reg>>2
  const int lane_src = (((tid >> 5) & 1) << 5) | u;
  f32x4 z[4];
#pragma unroll
  for (int gg = 0; gg < 4; ++gg) {
#pragma unroll
    for (int j = 0; j < 4; ++j) {
      int e = c4 * 4 + j;
      z[gg][j] = ex[((0 + gg) * 2 + rh) * 1024 + e * 64 + lane_src]
               + ex[((4 + gg) * 2 + rh) * 1024 + e * 64 + lane_src];
    }
  }
#pragma unroll
  for (int j = 0; j < 4; ++j) {
    size_t idx = (size_t)(r0 + rb + j) * NU + (u0 + u);
    float iv = sigm(z[0][j] + bA[0]);
    float fv = sigm(z[1][j] + bA[1]);
    float gv = tanh_f(z[2][j] + bA[2]);
    float ov = sigm(z[3][j] + bA[3]);
    float cN = fv * cst[j] + iv * gv;
    cst[j] = cN;
    unsigned hv = f2bf(ov * tanh_f(cN));
    coh_store_bf16(hOut + idx, hv);
    if (hOut2) coh_store_bf16(hOut2 + idx, hv);
  }
}

// ---------------- persistent kernel: whole 126-step serial chain ----------------
__global__ __launch_bounds__(512, 1) void lstm_seq(
    const unsigned short* __restrict__ U1p, const unsigned short* __restrict__ U1pp,
    const unsigned short* __restrict__ W2U2p, const unsigned short* __restrict__ W1p,
    const unsigned short* __restrict__ x2,
    const float* __restrict__ b1, const float* __restrict__ b1p, const float* __restrict__ b2,
    unsigned short* __restrict__ h0, unsigned short* __restrict__ h1,
    unsigned short* __restrict__ hist, unsigned* __restrict__ flags)
{
  extern __shared__ unsigned short lds[];
  const int bid = blockIdx.x;
  const int xcd = bid & 7, slot = bid >> 3;
  const int u_blk = xcd * 4 + (slot >> 3);    // 0..31 -> per-XCD B slice 1MB, L2-resident
  const int m_blk = slot & 7;                 // 0..7
  const int r0 = m_blk * 64, u0 = u_blk * 32;
  const int tid = threadIdx.x;
  const int w = tid >> 6, kh = w >> 2, g = w & 3;
  const size_t HS = (size_t)NB * NU;
  unsigned* gf = flags + m_blk * 64;          // this group's 32-flag line

  // epilogue biases for this thread's unit column (4 gates each)
  const int ub = u0 + (tid & 31);
  f32x4 bW, bC1, bC2;
#pragma unroll
  for (int gg = 0; gg < 4; ++gg) {
    bW[gg]  = b1 [gg * NU + ub];
    bC1[gg] = b1p[gg * NU + ub];
    bC2[gg] = b2 [gg * NU + ub];
  }
  f32x4 cst = (f32x4){0.f, 0.f, 0.f, 0.f};    // c for rows rb..rb+3, col ub

  unsigned gen = 0;
  // warmup: h0 (zeroed) <-> h1; final h lands in h0-slot (also hist[0])
  for (int t = 0; t < NT; ++t) {
    const unsigned short* hi = (t & 1) ? h1 : h0;
    unsigned short* ho = (t & 1) ? h0 : h1;
    do_step<NF>(hi, U1p, x2, W1p, t, bW, cst, ho, (t == NT - 1) ? hist : nullptr,
                lds, r0, u0, kh, g, tid);
    gbar_grp(gf, u_blk, ++gen);
  }
  // AR: cell1 (U1'=Wd@W1+U1): h0->h1 ; cell2 (W2+U2): h1->h0 (+hist[s+1])
  for (int s = 0; s < NS - 1; ++s) {
    do_step<0>(h0, U1pp, nullptr, nullptr, 0, bC1, cst, h1, nullptr,
               lds, r0, u0, kh, g, tid);
    gbar_grp(gf, u_blk, ++gen);
    do_step<0>(h1, W2U2p, nullptr, nullptr, 0, bC2, cst, h0, hist + (size_t)(s + 1) * HS,
               lds, r0, u0, kh, g, tid);
    gbar_grp(gf, u_blk, ++gen);
  }
}

// ---------------- batched output projection: out[b][s][f] = hist[s][b]@Wd + bd ----------------
__global__ __launch_bounds__(256, 2) void pred_gemm(
    const unsigned short* __restrict__ H,    // [32*512][1024] bf16
    const unsigned short* __restrict__ Wdp,  // packed [128][128][8] bf16
    const float* __restrict__ bd, float* __restrict__ out)
{
  __shared__ unsigned short lds[32 * NU];
  const int tid = threadIdx.x;
  const int r0 = blockIdx.x * 32;
  for (int i = tid; i < 32 * 128; i += 256) {
    int r = i >> 7, cb = i & 127;
    uint4 v = *(const uint4*)(H + (size_t)(r0 + r) * NU + cb * 8);
    int off = r * 2048 + ((cb * 16) ^ ((r & 7) << 4));
    *(uint4*)((char*)lds + off) = v;
  }
  __syncthreads();
  const int w = tid >> 6, l = tid & 63, lr = l & 15, g4 = l >> 4;
  f32x4 acc[2][2];
#pragma unroll
  for (int a = 0; a < 2; ++a)
#pragma unroll
    for (int c = 0; c < 2; ++c) acc[a][c] = (f32x4){0.f, 0.f, 0.f, 0.f};
  const char* ldsb = (const char*)lds;
  const int arow0 = lr * 2048, arow1 = (16 + lr) * 2048, axor = (lr & 7) << 4;
  const int col0 = w * 32 + lr;
#pragma unroll 4
  for (int kc = 0; kc < 32; ++kc) {
    int kb = (kc * 64 + g4 * 16) ^ axor;
    short8 a0 = *(const short8*)(ldsb + arow0 + kb);
    short8 a1 = *(const short8*)(ldsb + arow1 + kb);
    size_t base = ((size_t)(kc * 4 + g4) * NF) * 8;
    short8 w0 = *(const short8*)(Wdp + base + (size_t)col0 * 8);
    short8 w1 = *(const short8*)(Wdp + base + (size_t)(col0 + 16) * 8);
    acc[0][0] = __builtin_amdgcn_mfma_f32_16x16x32_bf16(a0, w0, acc[0][0], 0, 0, 0);
    acc[1][0] = __builtin_amdgcn_mfma_f32_16x16x32_bf16(a1, w0, acc[1][0], 0, 0, 0);
    acc[0][1] = __builtin_amdgcn_mfma_f32_16x16x32_bf16(a0, w1, acc[0][1], 0, 0, 0);
    acc[1][1] = __builtin_amdgcn_mfma_f32_16x16x32_bf16(a1, w1, acc[1][1], 0, 0, 0);
  }
#pragma unroll
  for (int rt = 0; rt < 2; ++rt)
#pragma unroll
    for (int ct = 0; ct < 2; ++ct)
#pragma unroll
      for (int j = 0; j < 4; ++j) {
        int r = r0 + rt * 16 + g4 * 4 + j;
        int s = r >> 9, bb = r & 511;
        int f = w * 32 + ct * 16 + lr;
        out[((size_t)bb * NS + s) * NF + f] = acc[rt][ct][j] + bd[f];
      }
}

// ---------------- prep kernels ----------------
// x2 in [T][B][F] layout (contiguous per-step staging)
__global__ void prep_x(const float* __restrict__ in, const float* __restrict__ mean,
                       const float* __restrict__ var, unsigned short* __restrict__ x2) {
  int i = (blockIdx.x * 256 + threadIdx.x) * 4;
  int f = i & 127;
  int bt = i >> 7;
  int b = bt >> 6, t = bt & 63;
  float4 v = *(const float4*)(in + i);
  float vv[4] = {v.x, v.y, v.z, v.w};
  unsigned short o[4] __attribute__((aligned(8)));
#pragma unroll
  for (int j = 0; j < 4; ++j) {
    float inv = rsqrtf(var[f + j] + 1e-7f);
    float s = inv * inv;
    float m2 = mean[f + j] * (s + inv);   // double-normalization folded
    o[j] = f2bf(vv[j] * s - m2);
  }
  *(uint2*)(x2 + (((size_t)t * NB + b) << 7) + f) = *(const uint2*)o;
}

// P[(k/8)*N*8 + c*8 + k%8] = bf16(A[k][c] (+ A2[k][c]))
__global__ void prep_pack(const float* __restrict__ A, const float* __restrict__ A2,
                          unsigned short* __restrict__ P, int N) {
  int idx = blockIdx.x * 256 + threadIdx.x;
  int kg = idx / N, c = idx - kg * N;
  unsigned short o[8] __attribute__((aligned(16)));
#pragma unroll
  for (int j = 0; j < 8; ++j) {
    size_t e = (size_t)(kg * 8 + j) * N + c;
    float vv = A[e];
    if (A2) vv += A2[e];
    o[j] = f2bf(vv);
  }
  *(uint4*)(P + (size_t)idx * 8) = *(const uint4*)o;
}

// U1' = U1 + Wd@W1, packed.  Wd slice staged in LDS; m-loop unrolled.
__global__ __launch_bounds__(256) void prep_u1pp(
    const float* __restrict__ U1, const float* __restrict__ Wd,
    const float* __restrict__ W1, unsigned short* __restrict__ P) {
  __shared__ float wd[8][NF];
  const int kg = blockIdx.x >> 4;
  const int c = ((blockIdx.x & 15) << 8) + threadIdx.x;
  for (int i = threadIdx.x; i < 8 * NF; i += 256)
    wd[i >> 7][i & 127] = Wd[(size_t)(kg * 8 + (i >> 7)) * NF + (i & 127)];
  __syncthreads();
  float a[8];
#pragma unroll
  for (int j = 0; j < 8; ++j) a[j] = U1[(size_t)(kg * 8 + j) * NG + c];
#pragma unroll 8
  for (int m = 0; m < NF; ++m) {
    float w1v = W1[(size_t)m * NG + c];
#pragma unroll
    for (int j = 0; j < 8; ++j) a[j] += wd[j][m] * w1v;
  }
  unsigned short o[8] __attribute__((aligned(16)));
#pragma unroll
  for (int j = 0; j < 8; ++j) o[j] = f2bf(a[j]);
  *(uint4*)(P + (size_t)(kg * NG + c) * 8) = *(const uint4*)o;
}

__global__ void prep_wdp(const float* __restrict__ Wd, unsigned short* __restrict__ P) {
  int idx = blockIdx.x * 256 + threadIdx.x;  // kg*128 + f
  int kg = idx >> 7, f = idx & 127;
  unsigned short o[8] __attribute__((aligned(16)));
#pragma unroll
  for (int j = 0; j < 8; ++j) o[j] = f2bf(Wd[(size_t)(kg * 8 + j) * NF + f]);
  *(uint4*)(P + (size_t)idx * 8) = *(const uint4*)o;
}

// b1' = b1 + bd@W1
__global__ void prep_b1p(const float* __restrict__ b1, const float* __restrict__ bd,
                         const float* __restrict__ W1, float* __restrict__ o) {
  int c = blockIdx.x * 256 + threadIdx.x;
  float acc = b1[c];
#pragma unroll 8
  for (int m = 0; m < NF; ++m) acc += bd[m] * W1[(size_t)m * NG + c];
  o[c] = acc;
}

extern "C" void kernel_launch(void* const* d_in, const int* in_sizes, int n_in,
                              void* d_out, int out_size, void* d_ws, size_t ws_size,
                              hipStream_t stream) {
  const float* inputs = (const float*)d_in[0];
  const float* mean = (const float*)d_in[1];
  const float* var  = (const float*)d_in[2];
  const float* W1   = (const float*)d_in[3];
  const float* U1   = (const float*)d_in[4];
  const float* b1   = (const float*)d_in[5];
  const float* W2   = (const float*)d_in[6];
  const float* U2   = (const float*)d_in[7];
  const float* b2   = (const float*)d_in[8];
  const float* Wd   = (const float*)d_in[9];
  const float* bd   = (const float*)d_in[10];
  float* out = (float*)d_out;
  char* ws = (char*)d_ws;

  size_t off = 0;
  auto alloc = [&](size_t bytes) { char* p = ws + off; off += (bytes + 255) & ~255ull; return p; };
  unsigned short* h0    = (unsigned short*)alloc((size_t)NB * NU * 2);
  unsigned short* h1    = (unsigned short*)alloc((size_t)NB * NU * 2);
  unsigned short* hist  = (unsigned short*)alloc((size_t)NS * NB * NU * 2);
  unsigned short* x2    = (unsigned short*)alloc((size_t)NB * NT * NF * 2);
  unsigned short* U1p   = (unsigned short*)alloc((size_t)NU * NG * 2);
  unsigned short* U1pp  = (unsigned short*)alloc((size_t)NU * NG * 2);
  unsigned short* W2U2p = (unsigned short*)alloc((size_t)NU * NG * 2);
  unsigned short* W1p   = (unsigned short*)alloc((size_t)NF * NG * 2);
  unsigned short* Wdp   = (unsigned short*)alloc((size_t)NU * NF * 2);
  float* b1p            = (float*)alloc((size_t)NG * 4);
  unsigned* flags       = (unsigned*)alloc(8 * 64 * 4);   // 8 groups x 64-word line

  hipMemsetAsync(h0, 0, (size_t)NB * NU * 2, stream);
  hipMemsetAsync(flags, 0, 8 * 64 * 4, stream);

  prep_x   <<<(NB * NT * NF) / 1024, 256, 0, stream>>>(inputs, mean, var, x2);
  prep_pack<<<(NU / 8) * NG / 256, 256, 0, stream>>>(U1, nullptr, U1p, NG);
  prep_u1pp<<<(NU / 8) * NG / 256, 256, 0, stream>>>(U1, Wd, W1, U1pp);
  prep_pack<<<(NU / 8) * NG / 256, 256, 0, stream>>>(W2, U2, W2U2p, NG);
  prep_pack<<<(NF / 8) * NG / 256, 256, 0, stream>>>(W1, nullptr, W1p, NG);
  prep_wdp <<<(NU / 8) * NF / 256, 256, 0, stream>>>(Wd, Wdp);
  prep_b1p <<<NG / 256, 256, 0, stream>>>(b1, bd, W1, b1p);

  // whole serial chain in one persistent kernel (64-row x 32-unit blocks,
  // 32x32x16 MFMA, gate-per-wave, all-wave epilogue; 32-block group barrier).
  // LDS = 64 rows x (1024+128) cols x 2B = 147456 B -> 1 block/CU.
  lstm_seq<<<256, 512, 64 * (NU + NF) * 2, stream>>>(U1p, U1pp, W2U2p, W1p, x2,
                                                     b1, b1p, b2, h0, h1, hist, flags);

  // all 32 output projections in one parallel GEMM
  pred_gemm<<<(NS * NB) / 32, 256, 0, stream>>>(hist, Wdp, bd, out);
}